// Round 1
// baseline (624.904 us; speedup 1.0000x reference)
//
#include <hip/hip_runtime.h>
#include <hip/hip_bf16.h>
#include <cstdio>
#include <cstdint>

typedef __bf16 bf16_t;
typedef __bf16 bf16x8 __attribute__((ext_vector_type(8)));
typedef float f32x4 __attribute__((ext_vector_type(4)));

static constexpr int Bc = 2, Sc = 1024, HIDc = 4096;
static constexpr int NQc = 32, NKVc = 8, Dc = 128, OFFc = 1024, Tc = 2048;
static constexpr int Mrows = Bc * Sc;                 // 2048
static constexpr int NQKV = (NQc + 2 * NKVc) * Dc;    // 6144

__device__ inline void load_lds16(const void* g, void* l) {
    __builtin_amdgcn_global_load_lds(
        (const __attribute__((address_space(1))) unsigned*)g,
        (__attribute__((address_space(3))) unsigned*)l, 16, 0, 0);
}

// ---------------- fp32 -> bf16 convert ----------------
__global__ void k_cvt(const float* __restrict__ src, bf16_t* __restrict__ dst, long n4) {
    long i = blockIdx.x * (long)blockDim.x + threadIdx.x;
    long stride = (long)gridDim.x * blockDim.x;
    const float4* s4 = (const float4*)src;
    for (; i < n4; i += stride) {
        float4 v = s4[i];
        bf16_t t[4] = {(bf16_t)v.x, (bf16_t)v.y, (bf16_t)v.z, (bf16_t)v.w};
        *(uint2*)&dst[i * 4] = *(uint2*)t;
    }
}

// ---------------- GEMM: C[M][N] = A[M][K] * B[N][K]^T (+bias) ----------------
// m97-style: 128x128 tile, BK=32, 4 waves (2x2), global_load_lds width-16.
template <bool BIAS, bool OUT_BF16>
__global__ __launch_bounds__(256) void k_gemm(const bf16_t* __restrict__ A,
                                              const bf16_t* __restrict__ Bm,
                                              const float* __restrict__ bias,
                                              void* __restrict__ Cout,
                                              int M, int N, int K) {
    __shared__ __align__(16) bf16_t As[128][32];
    __shared__ __align__(16) bf16_t Bs[128][32];
    const int tid = threadIdx.x, wid = tid >> 6, lane = tid & 63;
    const int g = lane >> 4, ln = lane & 15;
    const int wm = wid >> 1, wn = wid & 1;
    const int m0 = blockIdx.y * 128, n0 = blockIdx.x * 128;
    f32x4 acc[4][4] = {};

    for (int k0 = 0; k0 < K; k0 += 32) {
        __syncthreads();
#pragma unroll
        for (int c = 0; c < 2; ++c) {
            int row = wid * 32 + c * 16 + (lane >> 2);
            int col = (lane & 3) * 8;
            load_lds16(A + (size_t)(m0 + row) * K + k0 + col, &As[wid * 32 + c * 16][0]);
            load_lds16(Bm + (size_t)(n0 + row) * K + k0 + col, &Bs[wid * 32 + c * 16][0]);
        }
        __syncthreads();
        bf16x8 af[4], bfr[4];
#pragma unroll
        for (int i = 0; i < 4; ++i) af[i] = *(const bf16x8*)&As[wm * 64 + i * 16 + ln][g * 8];
#pragma unroll
        for (int i = 0; i < 4; ++i) bfr[i] = *(const bf16x8*)&Bs[wn * 64 + i * 16 + ln][g * 8];
#pragma unroll
        for (int i = 0; i < 4; ++i)
#pragma unroll
            for (int j = 0; j < 4; ++j)
                acc[i][j] = __builtin_amdgcn_mfma_f32_16x16x32_bf16(af[i], bfr[j], acc[i][j], 0, 0, 0);
    }

#pragma unroll
    for (int i = 0; i < 4; ++i) {
#pragma unroll
        for (int j = 0; j < 4; ++j) {
            int col = n0 + wn * 64 + j * 16 + ln;
            float bv = BIAS ? bias[col] : 0.f;
#pragma unroll
            for (int r = 0; r < 4; ++r) {
                int row = m0 + wm * 64 + i * 16 + g * 4 + r;
                float v = acc[i][j][r] + bv;
                if (OUT_BF16)
                    ((bf16_t*)Cout)[(size_t)row * N + col] = (bf16_t)v;
                else
                    ((float*)Cout)[(size_t)row * N + col] = v;
            }
        }
    }
}

// ---------------- RoPE + scatter of new K/V (and q in-place) ----------------
__global__ void k_rope(bf16_t* __restrict__ qkv, const float* __restrict__ cosT,
                       const float* __restrict__ sinT, float* __restrict__ kout,
                       float* __restrict__ vout, bf16_t* __restrict__ kfull,
                       bf16_t* __restrict__ vfull) {
    int row = blockIdx.x;            // 0..2047 = b*1024 + s
    int b = row >> 10, s = row & 1023;
    bf16_t* src = qkv + (size_t)row * NQKV;
    int tid = threadIdx.x;
    // q: 2048 pairs, rope in place
    for (int p = tid; p < 2048; p += 256) {
        int j = p & 63;
        float c = cosT[s * 64 + j], sn = sinT[s * 64 + j];
        float xr = (float)src[2 * p], xi = (float)src[2 * p + 1];
        src[2 * p]     = (bf16_t)(xr * c - xi * sn);
        src[2 * p + 1] = (bf16_t)(xr * sn + xi * c);
    }
    int t = OFFc + s;
    // k: 512 pairs, rope, broadcast to 4 query heads
    for (int p = tid; p < 512; p += 256) {
        int hk = p >> 6, j = p & 63;
        float c = cosT[s * 64 + j], sn = sinT[s * 64 + j];
        float xr = (float)src[NQc * Dc + 2 * p], xi = (float)src[NQc * Dc + 2 * p + 1];
        float orr = xr * c - xi * sn, oi = xr * sn + xi * c;
#pragma unroll
        for (int gg = 0; gg < 4; ++gg) {
            int hq = hk * 4 + gg;
            size_t o = (((size_t)b * Tc + t) * NQc + hq) * Dc + 2 * j;
            kout[o] = orr; kout[o + 1] = oi;
            kfull[o] = (bf16_t)orr; kfull[o + 1] = (bf16_t)oi;
        }
    }
    // v: 512 pairs, plain broadcast
    for (int p = tid; p < 512; p += 256) {
        int hk = p >> 6, j = p & 63;
        float xr = (float)src[(NQc + NKVc) * Dc + 2 * p];
        float xi = (float)src[(NQc + NKVc) * Dc + 2 * p + 1];
#pragma unroll
        for (int gg = 0; gg < 4; ++gg) {
            int hq = hk * 4 + gg;
            size_t o = (((size_t)b * Tc + t) * NQc + hq) * Dc + 2 * j;
            vout[o] = xr; vout[o + 1] = xi;
            vfull[o] = (bf16_t)xr; vfull[o + 1] = (bf16_t)xi;
        }
    }
}

// ---------------- cache copy (fp32 passthrough + bf16 shadow) ----------------
__global__ void k_cache(const float4* __restrict__ kc, const float4* __restrict__ vc,
                        float* __restrict__ ko, float* __restrict__ vo,
                        bf16_t* __restrict__ kf, bf16_t* __restrict__ vf) {
    const long n4 = (long)Bc * OFFc * NQc * Dc / 4;
    const long chunk = (long)OFFc * NQc * Dc;
    for (long i = blockIdx.x * (long)blockDim.x + threadIdx.x; i < n4;
         i += (long)gridDim.x * blockDim.x) {
        long e = i * 4;
        long b = e / chunk;
        long rem = e - b * chunk;
        size_t d = (size_t)b * ((size_t)Tc * NQc * Dc) + rem;
        float4 kv = kc[i];
        *(float4*)&ko[d] = kv;
        bf16_t t1[4] = {(bf16_t)kv.x, (bf16_t)kv.y, (bf16_t)kv.z, (bf16_t)kv.w};
        *(uint2*)&kf[d] = *(uint2*)t1;
        float4 vv = vc[i];
        *(float4*)&vo[d] = vv;
        bf16_t t2[4] = {(bf16_t)vv.x, (bf16_t)vv.y, (bf16_t)vv.z, (bf16_t)vv.w};
        *(uint2*)&vf[d] = *(uint2*)t2;
    }
}

// ---------------- flash attention ----------------
// Block: 4 waves x 16 q-rows (QT=64); K-tile 64, K row-major padded, V transposed.
__global__ __launch_bounds__(256) void k_attn(const bf16_t* __restrict__ qkv,
                                              const bf16_t* __restrict__ kfull,
                                              const bf16_t* __restrict__ vfull,
                                              bf16_t* __restrict__ attn) {
    __shared__ __align__(16) bf16_t Ks[64][136];
    __shared__ __align__(16) bf16_t Vt[128][72];
    __shared__ __align__(16) bf16_t Pl[4][16][72];
    const int tid = threadIdx.x, wid = tid >> 6, lane = tid & 63;
    const int g = lane >> 4, ln = lane & 15;
    const int q0 = blockIdx.x * 64;
    const int bh = blockIdx.y, b = bh >> 5, h = bh & 31;
    const float SCALE = 0.08838834764831845f;   // 1/sqrt(128)
    const float L2E = 1.4426950408889634f;

    bf16x8 qf[4];
    {
        size_t qrow = (size_t)(b * Sc + q0 + wid * 16 + ln) * NQKV + h * Dc;
#pragma unroll
        for (int dc = 0; dc < 4; ++dc) qf[dc] = *(const bf16x8*)&qkv[qrow + dc * 32 + g * 8];
    }
    f32x4 o[8] = {};
    float mrun[4] = {-1e30f, -1e30f, -1e30f, -1e30f};
    float lrun[4] = {0.f, 0.f, 0.f, 0.f};
    const int ntiles = (OFFc + q0) / 64 + 1;

    for (int t = 0; t < ntiles; ++t) {
        __syncthreads();
        {   // stage K (row-major) and V (transposed)
            int rr = tid >> 2;
            int d0 = (tid & 3) * 32;
            const bf16_t* kg = kfull + (((size_t)b * Tc + t * 64 + rr) * NQc + h) * Dc + d0;
            const bf16_t* vg = vfull + (((size_t)b * Tc + t * 64 + rr) * NQc + h) * Dc + d0;
#pragma unroll
            for (int c = 0; c < 4; ++c)
                *(uint4*)&Ks[rr][d0 + c * 8] = *(const uint4*)&kg[c * 8];
#pragma unroll
            for (int c = 0; c < 4; ++c) {
                bf16x8 vv = *(const bf16x8*)&vg[c * 8];
#pragma unroll
                for (int e = 0; e < 8; ++e) Vt[d0 + c * 8 + e][rr] = vv[e];
            }
        }
        __syncthreads();

        f32x4 sa[4] = {};
#pragma unroll
        for (int nf = 0; nf < 4; ++nf)
#pragma unroll
            for (int dc = 0; dc < 4; ++dc) {
                bf16x8 kf8 = *(const bf16x8*)&Ks[nf * 16 + ln][dc * 32 + g * 8];
                sa[nf] = __builtin_amdgcn_mfma_f32_16x16x32_bf16(qf[dc], kf8, sa[nf], 0, 0, 0);
            }

        float sv[4][4];
        bool last = (t == ntiles - 1);
#pragma unroll
        for (int nf = 0; nf < 4; ++nf)
#pragma unroll
            for (int r = 0; r < 4; ++r) {
                float s = sa[nf][r] * SCALE;
                if (last) {
                    int tg = t * 64 + nf * 16 + ln;
                    int qg = q0 + wid * 16 + g * 4 + r;
                    if (tg > OFFc + qg) s = -1e30f;
                }
                sv[nf][r] = s;
            }

        float al[4];
#pragma unroll
        for (int r = 0; r < 4; ++r) {
            float tm = fmaxf(fmaxf(sv[0][r], sv[1][r]), fmaxf(sv[2][r], sv[3][r]));
#pragma unroll
            for (int msk = 1; msk < 16; msk <<= 1) tm = fmaxf(tm, __shfl_xor(tm, msk));
            float mn = fmaxf(mrun[r], tm);
            al[r] = exp2f((mrun[r] - mn) * L2E);
            mrun[r] = mn;
        }
        float ps[4] = {0.f, 0.f, 0.f, 0.f};
#pragma unroll
        for (int nf = 0; nf < 4; ++nf)
#pragma unroll
            for (int r = 0; r < 4; ++r) {
                float p = exp2f((sv[nf][r] - mrun[r]) * L2E);
                ps[r] += p;
                Pl[wid][g * 4 + r][nf * 16 + ln] = (bf16_t)p;
            }
#pragma unroll
        for (int r = 0; r < 4; ++r) {
#pragma unroll
            for (int msk = 1; msk < 16; msk <<= 1) ps[r] += __shfl_xor(ps[r], msk);
            lrun[r] = lrun[r] * al[r] + ps[r];
        }
#pragma unroll
        for (int df = 0; df < 8; ++df) {
            f32x4 t4 = o[df];
            t4[0] *= al[0]; t4[1] *= al[1]; t4[2] *= al[2]; t4[3] *= al[3];
            o[df] = t4;
        }
#pragma unroll
        for (int kc = 0; kc < 2; ++kc) {
            bf16x8 pa = *(const bf16x8*)&Pl[wid][ln][kc * 32 + g * 8];
#pragma unroll
            for (int df = 0; df < 8; ++df) {
                bf16x8 bv = *(const bf16x8*)&Vt[df * 16 + ln][kc * 32 + g * 8];
                o[df] = __builtin_amdgcn_mfma_f32_16x16x32_bf16(pa, bv, o[df], 0, 0, 0);
            }
        }
    }

#pragma unroll
    for (int df = 0; df < 8; ++df)
#pragma unroll
        for (int r = 0; r < 4; ++r) {
            float v = o[df][r] / lrun[r];
            size_t orow = (size_t)(b * Sc + q0 + wid * 16 + g * 4 + r) * (NQc * Dc) + h * Dc + df * 16 + ln;
            attn[orow] = (bf16_t)v;
        }
}

extern "C" void kernel_launch(void* const* d_in, const int* in_sizes, int n_in,
                              void* d_out, int out_size, void* d_ws, size_t ws_size,
                              hipStream_t stream) {
    const float* x      = (const float*)d_in[0];
    const float* cosT   = (const float*)d_in[2];
    const float* sinT   = (const float*)d_in[3];
    const float* kcache = (const float*)d_in[4];
    const float* vcache = (const float*)d_in[5];
    const float* q_w    = (const float*)d_in[6];
    const float* q_b    = (const float*)d_in[7];
    const float* k_w    = (const float*)d_in[8];
    const float* k_b    = (const float*)d_in[9];
    const float* v_w    = (const float*)d_in[10];
    const float* v_b    = (const float*)d_in[11];
    const float* o_w    = (const float*)d_in[12];

    char* ws = (char*)d_ws;
    size_t off = 0;
    auto alloc = [&](size_t bytes) {
        void* p = ws + off;
        off += (bytes + 255) & ~(size_t)255;
        return p;
    };
    // region A: x_bf (dead after QKV GEMM) -> reused as attn
    bf16_t* xb   = (bf16_t*)alloc((size_t)Mrows * HIDc * 2);        // 16.8 MB
    // region B: wqkv (dead after QKV GEMM) -> reused as kfull+vfull
    bf16_t* wqkv = (bf16_t*)alloc((size_t)Bc * Tc * NQc * Dc * 4);  // 67.1 MB (>= 50.3 needed)
    bf16_t* owb  = (bf16_t*)alloc((size_t)HIDc * HIDc * 2);         // 33.6 MB
    bf16_t* qkv  = (bf16_t*)alloc((size_t)Mrows * NQKV * 2);        // 25.2 MB
    float*  bias = (float*)alloc((size_t)NQKV * 4);
    if (off > ws_size) {
        fprintf(stderr, "WS too small: need %zu have %zu\n", off, ws_size);
        return;
    }
    bf16_t* attn  = xb;
    bf16_t* kfull = wqkv;
    bf16_t* vfull = wqkv + (size_t)Bc * Tc * NQc * Dc;

    float* out_o = (float*)d_out;
    float* out_k = out_o + (size_t)Mrows * HIDc;
    float* out_v = out_k + (size_t)Bc * Tc * NQc * Dc;

    k_cvt<<<2048, 256, 0, stream>>>(x, xb, (long)Mrows * HIDc / 4);
    k_cvt<<<2048, 256, 0, stream>>>(q_w, wqkv, (long)NQc * Dc * HIDc / 4);
    k_cvt<<<1024, 256, 0, stream>>>(k_w, wqkv + (size_t)NQc * Dc * HIDc, (long)NKVc * Dc * HIDc / 4);
    k_cvt<<<1024, 256, 0, stream>>>(v_w, wqkv + (size_t)(NQc + NKVc) * Dc * HIDc, (long)NKVc * Dc * HIDc / 4);
    k_cvt<<<2048, 256, 0, stream>>>(o_w, owb, (long)HIDc * HIDc / 4);
    (void)hipMemcpyAsync(bias, q_b, (size_t)NQc * Dc * 4, hipMemcpyDeviceToDevice, stream);
    (void)hipMemcpyAsync(bias + NQc * Dc, k_b, (size_t)NKVc * Dc * 4, hipMemcpyDeviceToDevice, stream);
    (void)hipMemcpyAsync(bias + (NQc + NKVc) * Dc, v_b, (size_t)NKVc * Dc * 4, hipMemcpyDeviceToDevice, stream);

    k_gemm<true, true><<<dim3(NQKV / 128, Mrows / 128), 256, 0, stream>>>(
        xb, wqkv + 0, bias, qkv, Mrows, NQKV, HIDc);
    // NOTE: wqkv still holds weights here; kfull/vfull alias it but are only
    // written by the kernels below, which are stream-ordered after the GEMM.
    k_rope<<<Mrows, 256, 0, stream>>>(qkv, cosT, sinT, out_k, out_v, kfull, vfull);
    k_cache<<<2048, 256, 0, stream>>>((const float4*)kcache, (const float4*)vcache,
                                      out_k, out_v, kfull, vfull);
    k_attn<<<dim3(Sc / 64, Bc * NQc), 256, 0, stream>>>(qkv, kfull, vfull, attn);
    k_gemm<false, false><<<dim3(HIDc / 128, Mrows / 128), 256, 0, stream>>>(
        attn, owb, nullptr, d_out, Mrows, HIDc, HIDc);
}